// Round 9
// baseline (492.723 us; speedup 1.0000x reference)
//
#include <hip/hip_runtime.h>
#include <math.h>

#define QDIM 4096
#define NQ 12
#define QBATCH 2048

typedef _Float16 f16x8 __attribute__((ext_vector_type(8)));
typedef float f32x4 __attribute__((ext_vector_type(4)));
typedef int i32x4 __attribute__((ext_vector_type(4)));

__device__ __forceinline__ void gld_lds16(const void* gptr, void* ldsptr) {
    __builtin_amdgcn_global_load_lds(
        (const __attribute__((address_space(1))) void*)gptr,
        (__attribute__((address_space(3))) void*)ldsptr,
        16, 0, 0);
}

__device__ __forceinline__ int q8(float x) {
    float y = fminf(fmaxf(x, -127.f), 127.f);
    return (int)rintf(y);
}
__device__ __forceinline__ int pack4_i8(int a, int b, int c, int d) {
    return (a & 0xFF) | ((b & 0xFF) << 8) | ((c & 0xFF) << 16) | ((d & 0xFF) << 24);
}

// ---------------------------------------------------------------------------
// prep: blocks [0,4096): conv  — Eh = f16(E) both halves;
//                         G8[n,:] = i8((c0*E[n,:]+c1*E[n+2048,:])*127/6)
//       blocks [4096,6144): expand — A1 rows (Re, Im) + out[b]=0
// ---------------------------------------------------------------------------
__global__ __launch_bounds__(256) void prep_kernel(
    const float* __restrict__ E, const float* __restrict__ inputs,
    const float* __restrict__ wgt,
    _Float16* __restrict__ Eh, signed char* __restrict__ G8,
    _Float16* __restrict__ A1, float* __restrict__ out)
{
    const int tid = threadIdx.x;
    if (blockIdx.x < 4096) {
        // ---- conv ----
        float th = 0.5f * (wgt[0] + wgt[1] + wgt[2]);
        float c0 = cosf(th), c1 = -sinf(th);
        const float qs = 127.f / 6.f;
        size_t flat = ((size_t)blockIdx.x * 256 + tid) * 8;   // [0, 2048*4096)
        size_t n = flat >> 12;
        size_t k = flat & (QDIM - 1);
        const float* p0 = E + n * QDIM + k;
        const float* p1 = p0 + (size_t)QBATCH * QDIM;
        float4 a0 = ((const float4*)p0)[0], a1 = ((const float4*)p0)[1];
        float4 b0 = ((const float4*)p1)[0], b1 = ((const float4*)p1)[1];
        f16x8 h0 = { (_Float16)a0.x, (_Float16)a0.y, (_Float16)a0.z, (_Float16)a0.w,
                     (_Float16)a1.x, (_Float16)a1.y, (_Float16)a1.z, (_Float16)a1.w };
        f16x8 h1 = { (_Float16)b0.x, (_Float16)b0.y, (_Float16)b0.z, (_Float16)b0.w,
                     (_Float16)b1.x, (_Float16)b1.y, (_Float16)b1.z, (_Float16)b1.w };
        *(f16x8*)&Eh[n * QDIM + k] = h0;
        *(f16x8*)&Eh[(n + QBATCH) * QDIM + k] = h1;
        float g[8] = { c0*a0.x + c1*b0.x, c0*a0.y + c1*b0.y, c0*a0.z + c1*b0.z, c0*a0.w + c1*b0.w,
                       c0*a1.x + c1*b1.x, c0*a1.y + c1*b1.y, c0*a1.z + c1*b1.z, c0*a1.w + c1*b1.w };
        int2 gp = { pack4_i8(q8(g[0]*qs), q8(g[1]*qs), q8(g[2]*qs), q8(g[3]*qs)),
                    pack4_i8(q8(g[4]*qs), q8(g[5]*qs), q8(g[6]*qs), q8(g[7]*qs)) };
        *(int2*)&G8[n * QDIM + k] = gp;
    } else {
        // ---- expand ----
        __shared__ float ab[NQ][4];
        const int b = blockIdx.x - 4096;
        if (tid == 0) out[b] = 0.f;
        if (tid < NQ) {
            float x = inputs[b * NQ + tid];
            float ry = 0.5f * x;
            float rz = 0.5f * x * x;
            float ca = cosf(ry), sa = sinf(ry), cz = cosf(rz), sz = sinf(rz);
            ab[tid][0] = ca * cz;  ab[tid][1] = -ca * sz;
            ab[tid][2] = sa * cz;  ab[tid][3] =  sa * sz;
        }
        __syncthreads();
        float pr0 = 1.f, pi0 = 0.f;
#pragma unroll
        for (int q = 0; q < 8; ++q) {
            int bit = (tid >> (7 - q)) & 1;
            float cr = ab[q][bit * 2 + 0], ci = ab[q][bit * 2 + 1];
            float nr = pr0 * cr - pi0 * ci;
            float ni = pr0 * ci + pi0 * cr;
            pr0 = nr; pi0 = ni;
        }
        f16x8 vr[2], vi[2];
#pragma unroll
        for (int u = 0; u < 16; ++u) {
            float pr = pr0, pi = pi0;
#pragma unroll
            for (int q = 8; q < 12; ++q) {
                int bit = (u >> (11 - q)) & 1;
                float cr = ab[q][bit * 2 + 0], ci = ab[q][bit * 2 + 1];
                float nr = pr * cr - pi * ci;
                float ni = pr * ci + pi * cr;
                pr = nr; pi = ni;
            }
            vr[u >> 3][u & 7] = (_Float16)pr;
            vi[u >> 3][u & 7] = (_Float16)pi;
        }
        const int idx0 = tid * 16;
        *(f16x8*)&A1[(size_t)b * QDIM + idx0] = vr[0];
        *(f16x8*)&A1[(size_t)b * QDIM + idx0 + 8] = vr[1];
        *(f16x8*)&A1[(size_t)(b + QBATCH) * QDIM + idx0] = vi[0];
        *(f16x8*)&A1[(size_t)(b + QBATCH) * QDIM + idx0 + 8] = vi[1];
    }
}

// ---------------------------------------------------------------------------
// GEMM1 (f16, flatmm-style): C[m,n] = sum_k A[m,k]*B[n,k]. 128x128 tile,
// BK=64. Only B staged via global_load_lds into XOR-swizzled LDS; the B tile
// is 128 rows x 128 B = 1024 x 16B chunks -> 4 chunks per thread (the round-8
// bug staged only 2). A-fragments loaded directly global->VGPR (per instr:
// 16 rows x 64 B contiguous — full-line coalescing, L2-served). A-loads are
// issued before the barrier so the vmcnt drain covers their latency.
// 4 waves 2x2, 4x4 16x16x32 acc per wave.
// ---------------------------------------------------------------------------
__global__ __launch_bounds__(256) void gemm_f16(
    const _Float16* __restrict__ A, const _Float16* __restrict__ B,
    _Float16* __restrict__ C, int N)
{
    const int K = QDIM;
    __shared__ __attribute__((aligned(16))) _Float16 Bs[128 * 64];  // 16 KB

    const int tid  = threadIdx.x;
    const int wave = tid >> 6;
    const int lane = tid & 63;
    const int bn0 = blockIdx.x * 128;
    const int bm0 = blockIdx.y * 128;
    const int wm = (wave >> 1) * 64;
    const int wn = (wave & 1) * 64;
    const int q = lane >> 4;
    const int r = lane & 15;
    const int rx = r & 7;

    f32x4 acc[4][4];
#pragma unroll
    for (int i = 0; i < 4; ++i)
#pragma unroll
        for (int j = 0; j < 4; ++j) acc[i][j] = (f32x4){0.f, 0.f, 0.f, 0.f};

    // B staging: 1024 chunks of 16B, 4 per thread; LDS pos (row, p) holds
    // global chunk p ^ (row&7)  [proven conflict-free]
    const _Float16* gB[4];
    char* lB[4];
#pragma unroll
    for (int n = 0; n < 4; ++n) {
        int c = n * 256 + tid;
        int row = c >> 3;
        int gcol = (c & 7) ^ (row & 7);
        gB[n] = B + (size_t)(bn0 + row) * K + gcol * 8;
        lB[n] = (char*)Bs + (n * 256 + wave * 64) * 16;
    }
    // A fragment base pointers: frag (i) = row wm+i*16+r, 16B at col q*8
    const _Float16* pA[4];
#pragma unroll
    for (int i = 0; i < 4; ++i)
        pA[i] = A + (size_t)(bm0 + wm + i * 16 + r) * K + q * 8;

    for (int kk = 0; kk < K; kk += 64) {
#pragma unroll
        for (int n = 0; n < 4; ++n)
            gld_lds16(gB[n] + kk, lB[n]);
        f16x8 af[2][4];
#pragma unroll
        for (int s = 0; s < 2; ++s)
#pragma unroll
            for (int i = 0; i < 4; ++i)
                af[s][i] = *(const f16x8*)(pA[i] + kk + s * 32);
        __syncthreads();   // drains vmcnt: B tile in LDS, af in regs

#pragma unroll
        for (int s = 0; s < 2; ++s) {
            f16x8 bf[4];
#pragma unroll
            for (int j = 0; j < 4; ++j) {
                int row = wn + j * 16 + r;
                bf[j] = *(const f16x8*)&Bs[(row * 8 + ((s * 4 + q) ^ rx)) * 8];
            }
#pragma unroll
            for (int i = 0; i < 4; ++i)
#pragma unroll
                for (int j = 0; j < 4; ++j)
                    acc[i][j] = __builtin_amdgcn_mfma_f32_16x16x32_f16(af[s][i], bf[j], acc[i][j], 0, 0, 0);
        }
        __syncthreads();   // LDS reads done before next stage overwrites
    }

    // C/D layout: col = r, row = q*4 + reg
#pragma unroll
    for (int i = 0; i < 4; ++i) {
        const int crow = bm0 + wm + i * 16 + q * 4;
#pragma unroll
        for (int rr = 0; rr < 4; ++rr)
#pragma unroll
            for (int j = 0; j < 4; ++j)
                C[(size_t)(crow + rr) * N + bn0 + wn + j * 16 + r] = (_Float16)acc[i][j][rr];
    }
}

// ---------------------------------------------------------------------------
// Butterfly (3-phase register FFT): u2 = R u1 per complex row -> i8 + scale.
// ---------------------------------------------------------------------------
__global__ __launch_bounds__(256) void butterfly_kernel(
    const _Float16* __restrict__ u1, const float* __restrict__ wgt,
    signed char* __restrict__ A2, float* __restrict__ scaleA)
{
    __shared__ float sRe[4366];
    __shared__ float sIm[4366];
    __shared__ float mats[NQ][8];
    __shared__ float red[8];
    const int blk = blockIdx.x;
    const int tid = threadIdx.x;
    const int ah = tid >> 4;
    const int al = tid & 15;

    if (tid < NQ) {
        float tx = 0.5f * wgt[3 + tid];
        float tz = 0.5f * wgt[15 + tid];
        float c = cosf(tx), s = sinf(tx), cz = cosf(tz), sz = sinf(tz);
        mats[tid][0] =  c * cz;  mats[tid][1] = -c * sz;
        mats[tid][2] =  s * sz;  mats[tid][3] = -s * cz;
        mats[tid][4] = -s * sz;  mats[tid][5] = -s * cz;
        mats[tid][6] =  c * cz;  mats[tid][7] =  c * sz;
    }

    float xr[16], xi[16];
    {
        const _Float16* pRe = u1 + (size_t)blk * QDIM + tid * 16;
        const _Float16* pIm = u1 + (size_t)(blk + QBATCH) * QDIM + tid * 16;
        f16x8 r0 = ((const f16x8*)pRe)[0], r1 = ((const f16x8*)pRe)[1];
        f16x8 i0 = ((const f16x8*)pIm)[0], i1 = ((const f16x8*)pIm)[1];
#pragma unroll
        for (int j = 0; j < 8; ++j) {
            xr[j] = (float)r0[j]; xr[8 + j] = (float)r1[j];
            xi[j] = (float)i0[j]; xi[8 + j] = (float)i1[j];
        }
    }
    __syncthreads();

#define BFLY_STAGE(arrR, arrI, K_, Q_)                                         \
    {                                                                          \
        const float m00r = mats[Q_][0], m00i = mats[Q_][1];                    \
        const float m01r = mats[Q_][2], m01i = mats[Q_][3];                    \
        const float m10r = mats[Q_][4], m10i = mats[Q_][5];                    \
        const float m11r = mats[Q_][6], m11i = mats[Q_][7];                    \
        _Pragma("unroll")                                                      \
        for (int t = 0; t < 8; ++t) {                                          \
            int i0 = ((t >> (K_)) << ((K_) + 1)) | (t & ((1 << (K_)) - 1));    \
            int i1 = i0 | (1 << (K_));                                         \
            float x0r = arrR[i0], x0i = arrI[i0];                              \
            float x1r = arrR[i1], x1i = arrI[i1];                              \
            arrR[i0] = m00r * x0r - m00i * x0i + m01r * x1r - m01i * x1i;      \
            arrI[i0] = m00r * x0i + m00i * x0r + m01r * x1i + m01i * x1r;      \
            arrR[i1] = m10r * x0r - m10i * x0i + m11r * x1r - m11i * x1i;      \
            arrI[i1] = m10r * x0i + m10i * x0r + m11r * x1i + m11i * x1r;      \
        }                                                                      \
    }

#pragma unroll
    for (int p = 0; p < 4; ++p) BFLY_STAGE(xr, xi, p, 11 - p);

#pragma unroll
    for (int c = 0; c < 16; ++c) {
        sRe[273 * ah + 17 * al + c] = xr[c];
        sIm[273 * ah + 17 * al + c] = xi[c];
    }
    __syncthreads();

    float yr[16], yi[16];
#pragma unroll
    for (int b = 0; b < 16; ++b) {
        yr[b] = sRe[273 * ah + 17 * b + al];
        yi[b] = sIm[273 * ah + 17 * b + al];
    }
#pragma unroll
    for (int p = 0; p < 4; ++p) BFLY_STAGE(yr, yi, p, 7 - p);

#pragma unroll
    for (int b = 0; b < 16; ++b) {
        sRe[273 * ah + 17 * b + al] = yr[b];
        sIm[273 * ah + 17 * b + al] = yi[b];
    }
    __syncthreads();

    float zr[16], zi[16];
#pragma unroll
    for (int a = 0; a < 16; ++a) {
        zr[a] = sRe[273 * a + 17 * ah + al];
        zi[a] = sIm[273 * a + 17 * ah + al];
    }
#pragma unroll
    for (int p = 0; p < 4; ++p) BFLY_STAGE(zr, zi, p, 3 - p);

    float mR = 0.f, mI = 0.f;
#pragma unroll
    for (int j = 0; j < 16; ++j) {
        mR = fmaxf(mR, fabsf(zr[j]));
        mI = fmaxf(mI, fabsf(zi[j]));
    }
#pragma unroll
    for (int off = 32; off > 0; off >>= 1) {
        mR = fmaxf(mR, __shfl_xor(mR, off, 64));
        mI = fmaxf(mI, __shfl_xor(mI, off, 64));
    }
    const int wid = tid >> 6;
    if ((tid & 63) == 0) { red[wid] = mR; red[4 + wid] = mI; }
    __syncthreads();
    mR = fmaxf(fmaxf(red[0], red[1]), fmaxf(red[2], red[3]));
    mI = fmaxf(fmaxf(red[4], red[5]), fmaxf(red[6], red[7]));
    mR = fmaxf(mR, 1e-30f);
    mI = fmaxf(mI, 1e-30f);
    if (tid == 0) {
        scaleA[blk] = mR / 127.f;
        scaleA[blk + QBATCH] = mI / 127.f;
    }
    const float invR = 127.f / mR, invI = 127.f / mI;

    signed char* oRe = A2 + (size_t)blk * QDIM + ah * 16 + al;
    signed char* oIm = A2 + (size_t)(blk + QBATCH) * QDIM + ah * 16 + al;
#pragma unroll
    for (int a = 0; a < 16; ++a) {
        oRe[a * 256] = (signed char)q8(zr[a] * invR);
        oIm[a * 256] = (signed char)q8(zi[a] * invI);
    }
#undef BFLY_STAGE
}

// ---------------------------------------------------------------------------
// GEMM2 (i8, flatmm-style, fused reduce): acc = A2 . G8^T (i32);
// out[m & 2047] += sum_n (acc * scaleA[m] * dqG)^2.
// Only G8 staged in LDS (128 rows x 128 B = 1024 chunks, 4/thread, XOR
// swizzle); A2-frags direct global->VGPR. 16x16x64 i8 MFMA, 4x4 acc per wave.
// ---------------------------------------------------------------------------
__global__ __launch_bounds__(256) void gemm2_i8(
    const signed char* __restrict__ A, const signed char* __restrict__ B,
    const float* __restrict__ scaleA, float* __restrict__ out)
{
    const int K = QDIM;  // bytes per row
    __shared__ __attribute__((aligned(16))) signed char Bs[128 * 128];  // 16 KB

    const int tid  = threadIdx.x;
    const int wave = tid >> 6;
    const int lane = tid & 63;
    const int bn0 = blockIdx.x * 128;
    const int bm0 = blockIdx.y * 128;
    const int wm = (wave >> 1) * 64;
    const int wn = (wave & 1) * 64;
    const int q = lane >> 4;
    const int r = lane & 15;
    const int rx = r & 7;

    i32x4 acc[4][4];
#pragma unroll
    for (int i = 0; i < 4; ++i)
#pragma unroll
        for (int j = 0; j < 4; ++j) acc[i][j] = (i32x4){0, 0, 0, 0};

    // B staging: 1024 chunks of 16B, 4 per thread
    const signed char* gB[4];
    char* lB[4];
#pragma unroll
    for (int n = 0; n < 4; ++n) {
        int c = n * 256 + tid;
        int row = c >> 3;
        int gcol = (c & 7) ^ (row & 7);
        gB[n] = B + (size_t)(bn0 + row) * K + gcol * 16;
        lB[n] = (char*)Bs + (n * 256 + wave * 64) * 16;
    }
    const signed char* pA[4];
#pragma unroll
    for (int i = 0; i < 4; ++i)
        pA[i] = A + (size_t)(bm0 + wm + i * 16 + r) * K + q * 16;

    for (int kk = 0; kk < K; kk += 128) {
#pragma unroll
        for (int n = 0; n < 4; ++n)
            gld_lds16(gB[n] + kk, lB[n]);
        i32x4 af[2][4];
#pragma unroll
        for (int s = 0; s < 2; ++s)
#pragma unroll
            for (int i = 0; i < 4; ++i)
                af[s][i] = *(const i32x4*)(pA[i] + kk + s * 64);
        __syncthreads();

#pragma unroll
        for (int s = 0; s < 2; ++s) {
            i32x4 bf[4];
#pragma unroll
            for (int j = 0; j < 4; ++j) {
                int row = wn + j * 16 + r;
                bf[j] = *(const i32x4*)&Bs[row * 128 + (((s * 4 + q) ^ rx) * 16)];
            }
#pragma unroll
            for (int i = 0; i < 4; ++i)
#pragma unroll
                for (int j = 0; j < 4; ++j)
                    acc[i][j] = __builtin_amdgcn_mfma_i32_16x16x64_i8(af[s][i], bf[j], acc[i][j], 0, 0, 0);
        }
        __syncthreads();
    }

    // C/D layout: col = r, row = q*4 + reg. Fused |.|^2 reduce.
    const float dqG = 6.f / 127.f;
#pragma unroll
    for (int i = 0; i < 4; ++i) {
#pragma unroll
        for (int rr = 0; rr < 4; ++rr) {
            const int row = bm0 + wm + i * 16 + q * 4 + rr;
            const float sc = scaleA[row] * dqG;
            float v = 0.f;
#pragma unroll
            for (int j = 0; j < 4; ++j) {
                float t = sc * (float)acc[i][j][rr];
                v = fmaf(t, t, v);
            }
            v += __shfl_xor(v, 1, 64);
            v += __shfl_xor(v, 2, 64);
            v += __shfl_xor(v, 4, 64);
            v += __shfl_xor(v, 8, 64);
            if (r == 0) atomicAdd(&out[row & (QBATCH - 1)], v);
        }
    }
}

// ---------------------------------------------------------------------------
extern "C" void kernel_launch(void* const* d_in, const int* in_sizes, int n_in,
                              void* d_out, int out_size, void* d_ws, size_t ws_size,
                              hipStream_t stream)
{
    const float* inputs = (const float*)d_in[0];   // [2048, 12]
    const float* weight = (const float*)d_in[1];   // [27]
    const float* E      = (const float*)d_in[2];   // [4096, 4096] fp32
    float* out = (float*)d_out;                    // [2048]

    char* ws = (char*)d_ws;
    const size_t MB = 1024 * 1024;
    _Float16*    Eh     = (_Float16*)   (ws + 0);         // 32 MB f16 [4096][4096]
    signed char* G8     = (signed char*)(ws + 32 * MB);   //  8 MB i8  [2048][4096]
    _Float16*    A1     = (_Float16*)   (ws + 40 * MB);   // 32 MB f16 [4096][4096]
    _Float16*    u1     = (_Float16*)   (ws + 72 * MB);   // 32 MB f16 [4096][4096]
    signed char* A2     = (signed char*)(ws + 104 * MB);  // 16 MB i8  [4096][4096]
    float*       scaleA = (float*)      (ws + 120 * MB);  // 16 KB

    // conv (4096 blocks) + expand (2048 blocks) in one dispatch
    prep_kernel<<<4096 + 2048, 256, 0, stream>>>(E, inputs, weight, Eh, G8, A1, out);
    // u1 = v @ Eh^T  (M=4096 Re/Im stacked, N=4096, K=4096), f16 flatmm
    gemm_f16<<<dim3(QDIM / 128, QDIM / 128), 256, 0, stream>>>(A1, Eh, u1, QDIM);
    // u2 = R u1 -> int8 rows + per-row scales
    butterfly_kernel<<<QBATCH, 256, 0, stream>>>(u1, weight, A2, scaleA);
    // out[b] = sum_n |(u2 @ G^T)[b / b+2048, n]|^2  (i8 flatmm, fused reduce)
    gemm2_i8<<<dim3(2048 / 128, QDIM / 128), 256, 0, stream>>>(A2, G8, scaleA, out);
}

// Round 11
// 325.240 us; speedup vs baseline: 1.5149x; 1.5149x over previous
//
#include <hip/hip_runtime.h>
#include <math.h>

#define QDIM 4096
#define NQ 12
#define QBATCH 2048

typedef _Float16 f16x8 __attribute__((ext_vector_type(8)));
typedef float f32x4 __attribute__((ext_vector_type(4)));
typedef int i32x4 __attribute__((ext_vector_type(4)));

__device__ __forceinline__ void gld_lds16(const void* gptr, void* ldsptr) {
    __builtin_amdgcn_global_load_lds(
        (const __attribute__((address_space(1))) void*)gptr,
        (__attribute__((address_space(3))) void*)ldsptr,
        16, 0, 0);
}

__device__ __forceinline__ int q8(float x) {
    float y = fminf(fmaxf(x, -127.f), 127.f);
    return (int)rintf(y);
}
__device__ __forceinline__ int pack4_i8(int a, int b, int c, int d) {
    return (a & 0xFF) | ((b & 0xFF) << 8) | ((c & 0xFF) << 16) | ((d & 0xFF) << 24);
}

// ---------------------------------------------------------------------------
// prep: blocks [0,4096): conv  — Eh = f16(E) both halves;
//                         G8[n,:] = i8((c0*E[n,:]+c1*E[n+2048,:])*127/6)
//       blocks [4096,6144): expand — A1 rows (Re, Im) + out[b]=0
// ---------------------------------------------------------------------------
__global__ __launch_bounds__(256) void prep_kernel(
    const float* __restrict__ E, const float* __restrict__ inputs,
    const float* __restrict__ wgt,
    _Float16* __restrict__ Eh, signed char* __restrict__ G8,
    _Float16* __restrict__ A1, float* __restrict__ out)
{
    const int tid = threadIdx.x;
    if (blockIdx.x < 4096) {
        // ---- conv ----
        float th = 0.5f * (wgt[0] + wgt[1] + wgt[2]);
        float c0 = cosf(th), c1 = -sinf(th);
        const float qs = 127.f / 6.f;
        size_t flat = ((size_t)blockIdx.x * 256 + tid) * 8;   // [0, 2048*4096)
        size_t n = flat >> 12;
        size_t k = flat & (QDIM - 1);
        const float* p0 = E + n * QDIM + k;
        const float* p1 = p0 + (size_t)QBATCH * QDIM;
        float4 a0 = ((const float4*)p0)[0], a1 = ((const float4*)p0)[1];
        float4 b0 = ((const float4*)p1)[0], b1 = ((const float4*)p1)[1];
        f16x8 h0 = { (_Float16)a0.x, (_Float16)a0.y, (_Float16)a0.z, (_Float16)a0.w,
                     (_Float16)a1.x, (_Float16)a1.y, (_Float16)a1.z, (_Float16)a1.w };
        f16x8 h1 = { (_Float16)b0.x, (_Float16)b0.y, (_Float16)b0.z, (_Float16)b0.w,
                     (_Float16)b1.x, (_Float16)b1.y, (_Float16)b1.z, (_Float16)b1.w };
        *(f16x8*)&Eh[n * QDIM + k] = h0;
        *(f16x8*)&Eh[(n + QBATCH) * QDIM + k] = h1;
        float g[8] = { c0*a0.x + c1*b0.x, c0*a0.y + c1*b0.y, c0*a0.z + c1*b0.z, c0*a0.w + c1*b0.w,
                       c0*a1.x + c1*b1.x, c0*a1.y + c1*b1.y, c0*a1.z + c1*b1.z, c0*a1.w + c1*b1.w };
        int2 gp = { pack4_i8(q8(g[0]*qs), q8(g[1]*qs), q8(g[2]*qs), q8(g[3]*qs)),
                    pack4_i8(q8(g[4]*qs), q8(g[5]*qs), q8(g[6]*qs), q8(g[7]*qs)) };
        *(int2*)&G8[n * QDIM + k] = gp;
    } else {
        // ---- expand ----
        __shared__ float ab[NQ][4];
        const int b = blockIdx.x - 4096;
        if (tid == 0) out[b] = 0.f;
        if (tid < NQ) {
            float x = inputs[b * NQ + tid];
            float ry = 0.5f * x;
            float rz = 0.5f * x * x;
            float ca = cosf(ry), sa = sinf(ry), cz = cosf(rz), sz = sinf(rz);
            ab[tid][0] = ca * cz;  ab[tid][1] = -ca * sz;
            ab[tid][2] = sa * cz;  ab[tid][3] =  sa * sz;
        }
        __syncthreads();
        float pr0 = 1.f, pi0 = 0.f;
#pragma unroll
        for (int q = 0; q < 8; ++q) {
            int bit = (tid >> (7 - q)) & 1;
            float cr = ab[q][bit * 2 + 0], ci = ab[q][bit * 2 + 1];
            float nr = pr0 * cr - pi0 * ci;
            float ni = pr0 * ci + pi0 * cr;
            pr0 = nr; pi0 = ni;
        }
        f16x8 vr[2], vi[2];
#pragma unroll
        for (int u = 0; u < 16; ++u) {
            float pr = pr0, pi = pi0;
#pragma unroll
            for (int q = 8; q < 12; ++q) {
                int bit = (u >> (11 - q)) & 1;
                float cr = ab[q][bit * 2 + 0], ci = ab[q][bit * 2 + 1];
                float nr = pr * cr - pi * ci;
                float ni = pr * ci + pi * cr;
                pr = nr; pi = ni;
            }
            vr[u >> 3][u & 7] = (_Float16)pr;
            vi[u >> 3][u & 7] = (_Float16)pi;
        }
        const int idx0 = tid * 16;
        *(f16x8*)&A1[(size_t)b * QDIM + idx0] = vr[0];
        *(f16x8*)&A1[(size_t)b * QDIM + idx0 + 8] = vr[1];
        *(f16x8*)&A1[(size_t)(b + QBATCH) * QDIM + idx0] = vi[0];
        *(f16x8*)&A1[(size_t)(b + QBATCH) * QDIM + idx0 + 8] = vi[1];
    }
}

// ---------------------------------------------------------------------------
// GEMM1 (f16, proven m97 structure — best known: 151 us, 910 TF):
// C[m,n] = sum_k A[m,k]*B[n,k]. 128x128 tile, BK=64, A+B staged via
// global_load_lds (4+4 chunks/thread), XOR-swizzled LDS (0 conflicts),
// 4 waves 2x2, 4x4 16x16x32 acc per wave.
// ---------------------------------------------------------------------------
__global__ __launch_bounds__(256) void gemm_f16(
    const _Float16* __restrict__ A, const _Float16* __restrict__ B,
    _Float16* __restrict__ C, int N)
{
    const int K = QDIM;
    __shared__ __attribute__((aligned(16))) _Float16 As[128 * 64];
    __shared__ __attribute__((aligned(16))) _Float16 Bs[128 * 64];

    const int tid  = threadIdx.x;
    const int wave = tid >> 6;
    const int lane = tid & 63;
    const int bn0 = blockIdx.x * 128;
    const int bm0 = blockIdx.y * 128;
    const int wm = (wave >> 1) * 64;
    const int wn = (wave & 1) * 64;
    const int q = lane >> 4;
    const int r = lane & 15;
    const int rx = r & 7;

    f32x4 acc[4][4];
#pragma unroll
    for (int i = 0; i < 4; ++i)
#pragma unroll
        for (int j = 0; j < 4; ++j) acc[i][j] = (f32x4){0.f, 0.f, 0.f, 0.f};

    // staging: 1024 16B chunks per matrix per stage, 4 per thread.
    // LDS pos (row, p) holds global chunk p ^ (row&7)  [conflict-free]
    const _Float16* gA[4];
    const _Float16* gB[4];
    char* lA[4];
    char* lB[4];
#pragma unroll
    for (int n = 0; n < 4; ++n) {
        int c = n * 256 + tid;
        int row = c >> 3;
        int gcol = (c & 7) ^ (row & 7);
        gA[n] = A + (size_t)(bm0 + row) * K + gcol * 8;
        gB[n] = B + (size_t)(bn0 + row) * K + gcol * 8;
        lA[n] = (char*)As + (n * 256 + wave * 64) * 16;
        lB[n] = (char*)Bs + (n * 256 + wave * 64) * 16;
    }

    for (int kk = 0; kk < K; kk += 64) {
#pragma unroll
        for (int n = 0; n < 4; ++n) {
            gld_lds16(gA[n] + kk, lA[n]);
            gld_lds16(gB[n] + kk, lB[n]);
        }
        __syncthreads();

#pragma unroll
        for (int s = 0; s < 2; ++s) {
            f16x8 af[4], bf[4];
#pragma unroll
            for (int i = 0; i < 4; ++i) {
                int row = wm + i * 16 + r;
                af[i] = *(const f16x8*)&As[(row * 8 + ((s * 4 + q) ^ rx)) * 8];
            }
#pragma unroll
            for (int j = 0; j < 4; ++j) {
                int row = wn + j * 16 + r;
                bf[j] = *(const f16x8*)&Bs[(row * 8 + ((s * 4 + q) ^ rx)) * 8];
            }
#pragma unroll
            for (int i = 0; i < 4; ++i)
#pragma unroll
                for (int j = 0; j < 4; ++j)
                    acc[i][j] = __builtin_amdgcn_mfma_f32_16x16x32_f16(af[i], bf[j], acc[i][j], 0, 0, 0);
        }
        __syncthreads();
    }

    // C/D layout: col = r, row = q*4 + reg
#pragma unroll
    for (int i = 0; i < 4; ++i) {
        const int crow = bm0 + wm + i * 16 + q * 4;
#pragma unroll
        for (int rr = 0; rr < 4; ++rr)
#pragma unroll
            for (int j = 0; j < 4; ++j)
                C[(size_t)(crow + rr) * N + bn0 + wn + j * 16 + r] = (_Float16)acc[i][j][rr];
    }
}

// ---------------------------------------------------------------------------
// Butterfly (3-phase register FFT): u2 = R u1 per complex row -> i8 + scale.
// ---------------------------------------------------------------------------
__global__ __launch_bounds__(256) void butterfly_kernel(
    const _Float16* __restrict__ u1, const float* __restrict__ wgt,
    signed char* __restrict__ A2, float* __restrict__ scaleA)
{
    __shared__ float sRe[4366];
    __shared__ float sIm[4366];
    __shared__ float mats[NQ][8];
    __shared__ float red[8];
    const int blk = blockIdx.x;
    const int tid = threadIdx.x;
    const int ah = tid >> 4;
    const int al = tid & 15;

    if (tid < NQ) {
        float tx = 0.5f * wgt[3 + tid];
        float tz = 0.5f * wgt[15 + tid];
        float c = cosf(tx), s = sinf(tx), cz = cosf(tz), sz = sinf(tz);
        mats[tid][0] =  c * cz;  mats[tid][1] = -c * sz;
        mats[tid][2] =  s * sz;  mats[tid][3] = -s * cz;
        mats[tid][4] = -s * sz;  mats[tid][5] = -s * cz;
        mats[tid][6] =  c * cz;  mats[tid][7] =  c * sz;
    }

    float xr[16], xi[16];
    {
        const _Float16* pRe = u1 + (size_t)blk * QDIM + tid * 16;
        const _Float16* pIm = u1 + (size_t)(blk + QBATCH) * QDIM + tid * 16;
        f16x8 r0 = ((const f16x8*)pRe)[0], r1 = ((const f16x8*)pRe)[1];
        f16x8 i0 = ((const f16x8*)pIm)[0], i1 = ((const f16x8*)pIm)[1];
#pragma unroll
        for (int j = 0; j < 8; ++j) {
            xr[j] = (float)r0[j]; xr[8 + j] = (float)r1[j];
            xi[j] = (float)i0[j]; xi[8 + j] = (float)i1[j];
        }
    }
    __syncthreads();

#define BFLY_STAGE(arrR, arrI, K_, Q_)                                         \
    {                                                                          \
        const float m00r = mats[Q_][0], m00i = mats[Q_][1];                    \
        const float m01r = mats[Q_][2], m01i = mats[Q_][3];                    \
        const float m10r = mats[Q_][4], m10i = mats[Q_][5];                    \
        const float m11r = mats[Q_][6], m11i = mats[Q_][7];                    \
        _Pragma("unroll")                                                      \
        for (int t = 0; t < 8; ++t) {                                          \
            int i0 = ((t >> (K_)) << ((K_) + 1)) | (t & ((1 << (K_)) - 1));    \
            int i1 = i0 | (1 << (K_));                                         \
            float x0r = arrR[i0], x0i = arrI[i0];                              \
            float x1r = arrR[i1], x1i = arrI[i1];                              \
            arrR[i0] = m00r * x0r - m00i * x0i + m01r * x1r - m01i * x1i;      \
            arrI[i0] = m00r * x0i + m00i * x0r + m01r * x1i + m01i * x1r;      \
            arrR[i1] = m10r * x0r - m10i * x0i + m11r * x1r - m11i * x1i;      \
            arrI[i1] = m10r * x0i + m10i * x0r + m11r * x1i + m11i * x1r;      \
        }                                                                      \
    }

#pragma unroll
    for (int p = 0; p < 4; ++p) BFLY_STAGE(xr, xi, p, 11 - p);

#pragma unroll
    for (int c = 0; c < 16; ++c) {
        sRe[273 * ah + 17 * al + c] = xr[c];
        sIm[273 * ah + 17 * al + c] = xi[c];
    }
    __syncthreads();

    float yr[16], yi[16];
#pragma unroll
    for (int b = 0; b < 16; ++b) {
        yr[b] = sRe[273 * ah + 17 * b + al];
        yi[b] = sIm[273 * ah + 17 * b + al];
    }
#pragma unroll
    for (int p = 0; p < 4; ++p) BFLY_STAGE(yr, yi, p, 7 - p);

#pragma unroll
    for (int b = 0; b < 16; ++b) {
        sRe[273 * ah + 17 * b + al] = yr[b];
        sIm[273 * ah + 17 * b + al] = yi[b];
    }
    __syncthreads();

    float zr[16], zi[16];
#pragma unroll
    for (int a = 0; a < 16; ++a) {
        zr[a] = sRe[273 * a + 17 * ah + al];
        zi[a] = sIm[273 * a + 17 * ah + al];
    }
#pragma unroll
    for (int p = 0; p < 4; ++p) BFLY_STAGE(zr, zi, p, 3 - p);

    float mR = 0.f, mI = 0.f;
#pragma unroll
    for (int j = 0; j < 16; ++j) {
        mR = fmaxf(mR, fabsf(zr[j]));
        mI = fmaxf(mI, fabsf(zi[j]));
    }
#pragma unroll
    for (int off = 32; off > 0; off >>= 1) {
        mR = fmaxf(mR, __shfl_xor(mR, off, 64));
        mI = fmaxf(mI, __shfl_xor(mI, off, 64));
    }
    const int wid = tid >> 6;
    if ((tid & 63) == 0) { red[wid] = mR; red[4 + wid] = mI; }
    __syncthreads();
    mR = fmaxf(fmaxf(red[0], red[1]), fmaxf(red[2], red[3]));
    mI = fmaxf(fmaxf(red[4], red[5]), fmaxf(red[6], red[7]));
    mR = fmaxf(mR, 1e-30f);
    mI = fmaxf(mI, 1e-30f);
    if (tid == 0) {
        scaleA[blk] = mR / 127.f;
        scaleA[blk + QBATCH] = mI / 127.f;
    }
    const float invR = 127.f / mR, invI = 127.f / mI;

    signed char* oRe = A2 + (size_t)blk * QDIM + ah * 16 + al;
    signed char* oIm = A2 + (size_t)(blk + QBATCH) * QDIM + ah * 16 + al;
#pragma unroll
    for (int a = 0; a < 16; ++a) {
        oRe[a * 256] = (signed char)q8(zr[a] * invR);
        oIm[a * 256] = (signed char)q8(zi[a] * invI);
    }
#undef BFLY_STAGE
}

// ---------------------------------------------------------------------------
// GEMM2 (i8 16x16x64, proven, fused reduce): acc = A2 . G8^T (i32);
// out[m & 2047] += sum_n (acc * scaleA[m] * dqG)^2. A+B staged (4+4
// chunks/thread), XOR swizzle, 4x4 acc per wave.
// ---------------------------------------------------------------------------
__global__ __launch_bounds__(256) void gemm2_i8(
    const signed char* __restrict__ A, const signed char* __restrict__ B,
    const float* __restrict__ scaleA, float* __restrict__ out)
{
    const int K = QDIM;  // bytes per row
    __shared__ __attribute__((aligned(16))) signed char As[128 * 128];
    __shared__ __attribute__((aligned(16))) signed char Bs[128 * 128];

    const int tid  = threadIdx.x;
    const int wave = tid >> 6;
    const int lane = tid & 63;
    const int bn0 = blockIdx.x * 128;
    const int bm0 = blockIdx.y * 128;
    const int wm = (wave >> 1) * 64;
    const int wn = (wave & 1) * 64;
    const int q = lane >> 4;
    const int r = lane & 15;
    const int rx = r & 7;

    i32x4 acc[4][4];
#pragma unroll
    for (int i = 0; i < 4; ++i)
#pragma unroll
        for (int j = 0; j < 4; ++j) acc[i][j] = (i32x4){0, 0, 0, 0};

    const signed char* gA[4];
    const signed char* gB[4];
    char* lA[4];
    char* lB[4];
#pragma unroll
    for (int n = 0; n < 4; ++n) {
        int c = n * 256 + tid;
        int row = c >> 3;
        int gcol = (c & 7) ^ (row & 7);
        gA[n] = A + (size_t)(bm0 + row) * K + gcol * 16;
        gB[n] = B + (size_t)(bn0 + row) * K + gcol * 16;
        lA[n] = (char*)As + (n * 256 + wave * 64) * 16;
        lB[n] = (char*)Bs + (n * 256 + wave * 64) * 16;
    }

    for (int kk = 0; kk < K; kk += 128) {
#pragma unroll
        for (int n = 0; n < 4; ++n) {
            gld_lds16(gA[n] + kk, lA[n]);
            gld_lds16(gB[n] + kk, lB[n]);
        }
        __syncthreads();

#pragma unroll
        for (int s = 0; s < 2; ++s) {
            i32x4 af[4], bf[4];
#pragma unroll
            for (int i = 0; i < 4; ++i) {
                int row = wm + i * 16 + r;
                af[i] = *(const i32x4*)&As[row * 128 + (((s * 4 + q) ^ rx) * 16)];
            }
#pragma unroll
            for (int j = 0; j < 4; ++j) {
                int row = wn + j * 16 + r;
                bf[j] = *(const i32x4*)&Bs[row * 128 + (((s * 4 + q) ^ rx) * 16)];
            }
#pragma unroll
            for (int i = 0; i < 4; ++i)
#pragma unroll
                for (int j = 0; j < 4; ++j)
                    acc[i][j] = __builtin_amdgcn_mfma_i32_16x16x64_i8(af[i], bf[j], acc[i][j], 0, 0, 0);
        }
        __syncthreads();
    }

    // C/D layout: col = r, row = q*4 + reg. Fused |.|^2 reduce.
    const float dqG = 6.f / 127.f;
#pragma unroll
    for (int i = 0; i < 4; ++i) {
#pragma unroll
        for (int rr = 0; rr < 4; ++rr) {
            const int row = bm0 + wm + i * 16 + q * 4 + rr;
            const float sc = scaleA[row] * dqG;
            float v = 0.f;
#pragma unroll
            for (int j = 0; j < 4; ++j) {
                float t = sc * (float)acc[i][j][rr];
                v = fmaf(t, t, v);
            }
            v += __shfl_xor(v, 1, 64);
            v += __shfl_xor(v, 2, 64);
            v += __shfl_xor(v, 4, 64);
            v += __shfl_xor(v, 8, 64);
            if (r == 0) atomicAdd(&out[row & (QBATCH - 1)], v);
        }
    }
}

// ---------------------------------------------------------------------------
extern "C" void kernel_launch(void* const* d_in, const int* in_sizes, int n_in,
                              void* d_out, int out_size, void* d_ws, size_t ws_size,
                              hipStream_t stream)
{
    const float* inputs = (const float*)d_in[0];   // [2048, 12]
    const float* weight = (const float*)d_in[1];   // [27]
    const float* E      = (const float*)d_in[2];   // [4096, 4096] fp32
    float* out = (float*)d_out;                    // [2048]

    char* ws = (char*)d_ws;
    const size_t MB = 1024 * 1024;
    _Float16*    Eh     = (_Float16*)   (ws + 0);         // 32 MB f16 [4096][4096]
    signed char* G8     = (signed char*)(ws + 32 * MB);   //  8 MB i8  [2048][4096]
    _Float16*    A1     = (_Float16*)   (ws + 40 * MB);   // 32 MB f16 [4096][4096]
    _Float16*    u1     = (_Float16*)   (ws + 72 * MB);   // 32 MB f16 [4096][4096]
    signed char* A2     = (signed char*)(ws + 104 * MB);  // 16 MB i8  [4096][4096]
    float*       scaleA = (float*)      (ws + 120 * MB);  // 16 KB

    // conv (4096 blocks) + expand (2048 blocks) in one dispatch
    prep_kernel<<<4096 + 2048, 256, 0, stream>>>(E, inputs, weight, Eh, G8, A1, out);
    // u1 = v @ Eh^T  (M=4096 Re/Im stacked, N=4096, K=4096), f16 m97 structure
    gemm_f16<<<dim3(QDIM / 128, QDIM / 128), 256, 0, stream>>>(A1, Eh, u1, QDIM);
    // u2 = R u1 -> int8 rows + per-row scales
    butterfly_kernel<<<QBATCH, 256, 0, stream>>>(u1, weight, A2, scaleA);
    // out[b] = sum_n |(u2 @ G^T)[b / b+2048, n]|^2  (i8 MFMA, fused reduce)
    gemm2_i8<<<dim3(2048 / 128, QDIM / 128), 256, 0, stream>>>(A2, G8, scaleA, out);
}